// Round 7
// baseline (162.911 us; speedup 1.0000x reference)
//
#include <hip/hip_runtime.h>

#define BB 2
#define SS 2048
#define DD 1024
#define HH 16
#define HDIM 64
#define MTOT 4096  // B*S

typedef unsigned short u16;
typedef __bf16 bf16_t;
typedef bf16_t bf16x8 __attribute__((ext_vector_type(8)));
typedef float floatx4 __attribute__((ext_vector_type(4)));
typedef float floatx16 __attribute__((ext_vector_type(16)));

__device__ __forceinline__ float bf2f(u16 u) {
  union { unsigned int i; float f; } x;
  x.i = ((unsigned int)u) << 16;
  return x.f;
}
// round-to-nearest-even f32 -> bf16 (finite inputs only)
__device__ __forceinline__ u16 f2bf(float f) {
  union { float f; unsigned int i; } x;
  x.f = f;
  unsigned int r = x.i + 0x7fffu + ((x.i >> 16) & 1u);
  return (u16)(r >> 16);
}

// ---------------- kernel 1: fp32 -> bf16 cast INTO K-PANEL layout ----------------
// dst[p][r][8] u16, p = k/8 (128 panels), entry = 16B. LDS-tiled 64x64 transpose
// so both global read (256B runs) and write (1KB runs per panel) are coalesced.
// grid: (112, 16): bx<64 -> hs row-tile; else weight seg/tile. by = col(k)-tile.
__global__ __launch_bounds__(256) void cast_panel(
    const float* __restrict__ hs, const float* __restrict__ wq,
    const float* __restrict__ wk, const float* __restrict__ wv,
    u16* __restrict__ hs_p, u16* __restrict__ wq_p,
    u16* __restrict__ wk_p, u16* __restrict__ wv_p) {
  __shared__ u16 sT[64 * 72];  // pad 72: panel-read b128 hits all 8 bank-quads
  const int bx = blockIdx.x, y = blockIdx.y;
  const float* src; u16* dst; int r0, R;
  if (bx < 64) { src = hs; dst = hs_p; r0 = bx * 64; R = 4096; }
  else {
    int w = (bx - 64) >> 4, t = (bx - 64) & 15;
    src = (w == 0) ? wq : (w == 1) ? wk : wv;
    dst = (w == 0) ? wq_p : (w == 1) ? wk_p : wv_p;
    r0 = t * 64; R = 1024;
  }
  const int c0 = y * 64;
  const int tid = threadIdx.x;
#pragma unroll
  for (int i = 0; i < 4; ++i) {
    int e = i * 256 + tid;           // 0..1023 float4 entries of the 64x64 tile
    int row = e >> 4, c4 = e & 15;
    float4 v = reinterpret_cast<const float4*>(src)[(size_t)(r0 + row) * 256 + (c0 >> 2) + c4];
    ushort4 o;
    o.x = f2bf(v.x); o.y = f2bf(v.y); o.z = f2bf(v.z); o.w = f2bf(v.w);
    *reinterpret_cast<ushort4*>(&sT[row * 72 + c4 * 4]) = o;
  }
  __syncthreads();
#pragma unroll
  for (int i = 0; i < 2; ++i) {
    int e = i * 256 + tid;           // 0..511: (p local 0..7) x (m 0..63)
    int p = e >> 6, m = e & 63;
    uint4 v = *reinterpret_cast<const uint4*>(&sT[m * 72 + p * 8]);
    reinterpret_cast<uint4*>(dst)[(size_t)(y * 8 + p) * R + r0 + m] = v;
  }
}

// ---------------- kernel 2: fused QKV projection — DIRECT-FROM-L2, no LDS, no barriers ----
// C[m,n] = sum_k A[m,k]*W[n,k] + bias[n]. Inputs in panel layout [k/8][rows][8] (16B/entry).
// Each MFMA fragment is a contiguous 512B global run per half-wave (panel rows), so waves
// load A/B fragments straight into VGPRs with global_load_dwordx4, register-double-buffered
// one BK=32 step ahead. No __shared__, no __syncthreads => compiler emits fine-grained
// vmcnt(N); loads stay in flight across iterations (the m97 2-barrier ceiling-breaker).
// Block = 4 waves, each a 64x64 sub-tile = 2x2 of 32x32x16 MFMA. Grid (24,32):
// linear_id%8 is y-invariant => all 32 m-tiles sharing one W-tile land on one XCD (L2 reuse).
__global__ __launch_bounds__(256) void qkv_gemm_kernel(
    const u16* __restrict__ Ap,
    const u16* __restrict__ Wqp, const u16* __restrict__ Wkp, const u16* __restrict__ Wvp,
    const float* __restrict__ bq, const float* __restrict__ bk, const float* __restrict__ bv,
    u16* __restrict__ Qo, u16* __restrict__ Ko, u16* __restrict__ Vo) {
  const int ntall = blockIdx.x, mt = blockIdx.y;
  const int seg = ntall >> 3, nt = ntall & 7;
  const u16* Wp = (seg == 0) ? Wqp : (seg == 1) ? Wkp : Wvp;
  const float* bp = (seg == 0) ? bq : (seg == 1) ? bk : bv;
  u16* Out = (seg == 0) ? Qo : (seg == 1) ? Ko : Vo;
  const int m0 = mt * 128, n0 = nt * 128;
  const int tid = threadIdx.x;
  const int lane = tid & 63, wave = tid >> 6;
  const int wm = (wave >> 1) * 64, wn = (wave & 1) * 64;
  const int l32 = lane & 31, khalf = lane >> 5;
  // per-lane base pointers (16B entries; u16 units = entry*8)
  const u16* apb = Ap + ((size_t)khalf * MTOT + m0 + wm + l32) * 8;
  const u16* bpb = Wp + ((size_t)khalf * 1024 + n0 + wn + l32) * 8;
  const size_t aStep = (size_t)4 * MTOT * 8;   // +4 panels per BK=32 step
  const size_t bStep = (size_t)4 * 1024 * 8;
  floatx16 acc[2][2] = {};

  auto loadfr = [&](bf16x8 (&a)[2][2], bf16x8 (&b)[2][2], int s) {
    const u16* ap = apb + (size_t)s * aStep;
    const u16* bp2 = bpb + (size_t)s * bStep;
#pragma unroll
    for (int kk = 0; kk < 2; ++kk)
#pragma unroll
      for (int i = 0; i < 2; ++i) {
        a[kk][i] = *reinterpret_cast<const bf16x8*>(ap + ((size_t)kk * 2 * MTOT + i * 32) * 8);
        b[kk][i] = *reinterpret_cast<const bf16x8*>(bp2 + ((size_t)kk * 2 * 1024 + i * 32) * 8);
      }
  };
  auto mfmall = [&](bf16x8 (&a)[2][2], bf16x8 (&b)[2][2]) {
#pragma unroll
    for (int kk = 0; kk < 2; ++kk)
#pragma unroll
      for (int i = 0; i < 2; ++i)
#pragma unroll
        for (int j = 0; j < 2; ++j)
          acc[i][j] = __builtin_amdgcn_mfma_f32_32x32x16_bf16(a[kk][i], b[kk][j], acc[i][j], 0, 0, 0);
  };

  bf16x8 aC[2][2], bC[2][2], aN[2][2], bN[2][2];
  loadfr(aC, bC, 0);
  for (int s = 0; s < 32; s += 2) {
    loadfr(aN, bN, s + 1);          // prefetch while MFMAs below execute
    mfmall(aC, bC);
    if (s + 2 < 32) loadfr(aC, bC, s + 2);
    mfmall(aN, bN);
  }
  // epilogue: C/D layout col=lane&31, row=(reg&3)+8*(reg>>2)+4*(lane>>5); row-major out.
#pragma unroll
  for (int j = 0; j < 2; ++j) {
    int col = n0 + wn + j * 32 + l32;
    float bias = bp[col];
#pragma unroll
    for (int i = 0; i < 2; ++i) {
#pragma unroll
      for (int reg = 0; reg < 16; ++reg) {
        int row = m0 + wm + i * 32 + (reg & 3) + 8 * (reg >> 2) + 4 * khalf;
        Out[(size_t)row * DD + col] = f2bf(acc[i][j][reg] + bias);
      }
    }
  }
}

// ---------------- kernel 3: mpart[pc][bh][e][d] = sum_{s in chunk pc} mask[s]*K[s,e]*V[s,d] ----------------
__global__ __launch_bounds__(256) void m_partial_kernel(
    const u16* __restrict__ Kb, const u16* __restrict__ Vb,
    const float* __restrict__ am, float* __restrict__ mpart) {
  __shared__ float sK[64 * 68];
  __shared__ float sV[64 * 68];
  const int bh = blockIdx.y;     // 0..31
  const int b = bh >> 4, h = bh & 15;
  const int tid = threadIdx.x;
  const int e0 = (tid & 15) * 4, d0 = (tid >> 4) * 4;
  float acc[4][4] = {};
  for (int cs = 0; cs < 4; ++cs) {
    const int s0 = (blockIdx.x * 4 + cs) * 64;
    if (cs) __syncthreads();  // protect LDS before restage
#pragma unroll
    for (int c = 0; c < 2; ++c) {
      int L = tid + c * 256;
      int srow = L >> 3;            // 0..63
      int col = (L & 7) * 8;        // 0..56
      size_t g = (size_t)(b * SS + s0 + srow) * DD + h * HDIM + col;
      uint4 kraw = *reinterpret_cast<const uint4*>(Kb + g);
      uint4 vraw = *reinterpret_cast<const uint4*>(Vb + g);
      float m = (am[b * SS + s0 + srow] >= 0.f) ? 1.f : 0.f;
      unsigned int kw[4] = {kraw.x, kraw.y, kraw.z, kraw.w};
      unsigned int vw[4] = {vraw.x, vraw.y, vraw.z, vraw.w};
#pragma unroll
      for (int q = 0; q < 4; ++q) {
        sK[srow * 68 + col + 2 * q]     = m * bf2f((u16)(kw[q] & 0xffffu));
        sK[srow * 68 + col + 2 * q + 1] = m * bf2f((u16)(kw[q] >> 16));
        sV[srow * 68 + col + 2 * q]     = bf2f((u16)(vw[q] & 0xffffu));
        sV[srow * 68 + col + 2 * q + 1] = bf2f((u16)(vw[q] >> 16));
      }
    }
    __syncthreads();
    for (int s = 0; s < 64; ++s) {
      float4 kk = *reinterpret_cast<const float4*>(&sK[s * 68 + e0]);
      float4 vv = *reinterpret_cast<const float4*>(&sV[s * 68 + d0]);
      float ka[4] = {kk.x, kk.y, kk.z, kk.w};
      float va[4] = {vv.x, vv.y, vv.z, vv.w};
#pragma unroll
      for (int i = 0; i < 4; ++i)
#pragma unroll
        for (int j = 0; j < 4; ++j) acc[i][j] += ka[i] * va[j];
    }
  }
  float* outp = mpart + ((size_t)(blockIdx.x * 32 + bh)) * 4096;
#pragma unroll
  for (int i = 0; i < 4; ++i) {
    float4 o = {acc[i][0], acc[i][1], acc[i][2], acc[i][3]};
    *reinterpret_cast<float4*>(&outp[(e0 + i) * 64 + d0]) = o;
  }
}

// ---------------- kernel 4: ctx[m, h*64+d] = sum_e Q[m, h*64+e] * M[bh,e,d] ----------------
__global__ __launch_bounds__(256) void ctx_kernel(
    const u16* __restrict__ Qb, const float* __restrict__ mpart, float* __restrict__ Out) {
  __shared__ float sM[64 * 68];
  __shared__ float sQ[64 * 68];
  const int mchunk = blockIdx.x;  // 0..63
  const int h = blockIdx.y;       // 0..15
  const int m0 = mchunk * 64;
  const int b = m0 >> 11;         // m0 / 2048
  const int bh = b * HH + h;
  const int tid = threadIdx.x;
#pragma unroll
  for (int c = 0; c < 4; ++c) {
    int L4 = c * 256 + tid;       // float4 index 0..1023 within the 64x64 M block
    float4 s = {0.f, 0.f, 0.f, 0.f};
#pragma unroll
    for (int pc = 0; pc < 8; ++pc) {
      const float4* p4 = reinterpret_cast<const float4*>(mpart + ((size_t)(pc * 32 + bh)) * 4096);
      float4 t = p4[L4];
      s.x += t.x; s.y += t.y; s.z += t.z; s.w += t.w;
    }
    int e = L4 >> 4, d = (L4 & 15) * 4;
    *reinterpret_cast<float4*>(&sM[e * 68 + d]) = s;
  }
#pragma unroll
  for (int c = 0; c < 2; ++c) {
    int L = tid + c * 256;
    int row = L >> 3, col = (L & 7) * 8;
    uint4 q = *reinterpret_cast<const uint4*>(Qb + (size_t)(m0 + row) * DD + h * HDIM + col);
    unsigned int w[4] = {q.x, q.y, q.z, q.w};
#pragma unroll
    for (int t = 0; t < 4; ++t) {
      sQ[row * 68 + col + 2 * t]     = bf2f((u16)(w[t] & 0xffffu));
      sQ[row * 68 + col + 2 * t + 1] = bf2f((u16)(w[t] >> 16));
    }
  }
  __syncthreads();
  const int d0 = (tid & 15) * 4, ml0 = (tid >> 4) * 4;
  float acc[4][4] = {};
  for (int e4 = 0; e4 < 64; e4 += 4) {
    float4 mm[4], qq[4];
#pragma unroll
    for (int t = 0; t < 4; ++t)
      mm[t] = *reinterpret_cast<const float4*>(&sM[(e4 + t) * 68 + d0]);
#pragma unroll
    for (int i = 0; i < 4; ++i)
      qq[i] = *reinterpret_cast<const float4*>(&sQ[(ml0 + i) * 68 + e4]);
    float ma[4][4], qa[4][4];
#pragma unroll
    for (int t = 0; t < 4; ++t) {
      ma[t][0] = mm[t].x; ma[t][1] = mm[t].y; ma[t][2] = mm[t].z; ma[t][3] = mm[t].w;
      qa[t][0] = qq[t].x; qa[t][1] = qq[t].y; qa[t][2] = qq[t].z; qa[t][3] = qq[t].w;
    }
#pragma unroll
    for (int i = 0; i < 4; ++i)
#pragma unroll
      for (int t = 0; t < 4; ++t)
#pragma unroll
        for (int j = 0; j < 4; ++j)
          acc[i][j] += qa[i][t] * ma[t][j];
  }
#pragma unroll
  for (int i = 0; i < 4; ++i) {
    float4 o = {acc[i][0], acc[i][1], acc[i][2], acc[i][3]};
    *reinterpret_cast<float4*>(Out + (size_t)(m0 + ml0 + i) * DD + h * HDIM + d0) = o;
  }
}

extern "C" void kernel_launch(void* const* d_in, const int* in_sizes, int n_in,
                              void* d_out, int out_size, void* d_ws, size_t ws_size,
                              hipStream_t stream) {
  const float* hs = (const float*)d_in[0];
  const float* am = (const float*)d_in[1];
  const float* wq = (const float*)d_in[2];
  const float* bq = (const float*)d_in[3];
  const float* wk = (const float*)d_in[4];
  const float* bk = (const float*)d_in[5];
  const float* wv = (const float*)d_in[6];
  const float* bv = (const float*)d_in[7];
  float* out = (float*)d_out;
  char* ws = (char*)d_ws;

  // workspace layout (bytes), all 16B-aligned; total ~44 MB
  u16* hs_p = (u16*)(ws);                  // 8 MiB  panel [128][4096][8] bf16
  u16* wq_p = (u16*)(ws + 8388608);        // 2 MiB  panel [128][1024][8]
  u16* wk_p = (u16*)(ws + 10485760);       // 2 MiB
  u16* wv_p = (u16*)(ws + 12582912);       // 2 MiB
  u16* q_b  = (u16*)(ws + 14680064);       // 8 MiB  row-major [4096][1024]
  u16* k_b  = (u16*)(ws + 23068672);       // 8 MiB
  u16* v_b  = (u16*)(ws + 31457280);       // 8 MiB
  float* mpart = (float*)(ws + 39845888);  // 4 MiB [8 pc][32 bh][64][64] f32

  cast_panel<<<dim3(112, 16), 256, 0, stream>>>(hs, wq, wk, wv, hs_p, wq_p, wk_p, wv_p);
  qkv_gemm_kernel<<<dim3(24, 32), 256, 0, stream>>>(hs_p, wq_p, wk_p, wv_p,
                                                    bq, bk, bv, q_b, k_b, v_b);
  m_partial_kernel<<<dim3(8, 32), 256, 0, stream>>>(k_b, v_b, am, mpart);
  ctx_kernel<<<dim3(64, 16), 256, 0, stream>>>(q_b, mpart, out);
}

// Round 8
// 156.721 us; speedup vs baseline: 1.0395x; 1.0395x over previous
//
#include <hip/hip_runtime.h>

#define BB 2
#define SS 2048
#define DD 1024
#define HH 16
#define HDIM 64
#define MTOT 4096  // B*S

typedef unsigned short u16;
typedef __bf16 bf16_t;
typedef bf16_t bf16x8 __attribute__((ext_vector_type(8)));
typedef float floatx4 __attribute__((ext_vector_type(4)));
typedef float floatx16 __attribute__((ext_vector_type(16)));

__device__ __forceinline__ float bf2f(u16 u) {
  union { unsigned int i; float f; } x;
  x.i = ((unsigned int)u) << 16;
  return x.f;
}
// round-to-nearest-even f32 -> bf16 (finite inputs only)
__device__ __forceinline__ u16 f2bf(float f) {
  union { float f; unsigned int i; } x;
  x.f = f;
  unsigned int r = x.i + 0x7fffu + ((x.i >> 16) & 1u);
  return (u16)(r >> 16);
}

// ---------------- kernel 1: fp32 -> bf16 cast INTO K-PANEL layout ----------------
// dst[p][r][8] u16, p = k/8 (128 panels), entry = 16B. LDS-tiled 64x64 transpose
// so both global read (256B runs) and write (1KB runs per panel) are coalesced.
__global__ __launch_bounds__(256) void cast_panel(
    const float* __restrict__ hs, const float* __restrict__ wq,
    const float* __restrict__ wk, const float* __restrict__ wv,
    u16* __restrict__ hs_p, u16* __restrict__ wq_p,
    u16* __restrict__ wk_p, u16* __restrict__ wv_p) {
  __shared__ u16 sT[64 * 72];  // pad 72: panel-read b128 hits all 8 bank-quads
  const int bx = blockIdx.x, y = blockIdx.y;
  const float* src; u16* dst; int r0, R;
  if (bx < 64) { src = hs; dst = hs_p; r0 = bx * 64; R = 4096; }
  else {
    int w = (bx - 64) >> 4, t = (bx - 64) & 15;
    src = (w == 0) ? wq : (w == 1) ? wk : wv;
    dst = (w == 0) ? wq_p : (w == 1) ? wk_p : wv_p;
    r0 = t * 64; R = 1024;
  }
  const int c0 = y * 64;
  const int tid = threadIdx.x;
#pragma unroll
  for (int i = 0; i < 4; ++i) {
    int e = i * 256 + tid;           // 0..1023 float4 entries of the 64x64 tile
    int row = e >> 4, c4 = e & 15;
    float4 v = reinterpret_cast<const float4*>(src)[(size_t)(r0 + row) * 256 + (c0 >> 2) + c4];
    ushort4 o;
    o.x = f2bf(v.x); o.y = f2bf(v.y); o.z = f2bf(v.z); o.w = f2bf(v.w);
    *reinterpret_cast<ushort4*>(&sT[row * 72 + c4 * 4]) = o;
  }
  __syncthreads();
#pragma unroll
  for (int i = 0; i < 2; ++i) {
    int e = i * 256 + tid;           // 0..511: (p local 0..7) x (m 0..63)
    int p = e >> 6, m = e & 63;
    uint4 v = *reinterpret_cast<const uint4*>(&sT[m * 72 + p * 8]);
    reinterpret_cast<uint4*>(dst)[(size_t)(y * 8 + p) * R + r0 + m] = v;
  }
}

// ---------------- kernel 2: fused QKV projection — DIRECT-FROM-L2, no LDS, no barriers ----
// Same K-loop as round 7 (register double-buffered, fine-grained vmcnt).
// GRID SWAPPED to (32, 24): blockIdx.x = m-tile, so XCD = linear%8 = mt%8.
// Per-XCD A working set = 4 m-tiles = 1 MB (L2-resident, was 8 MB thrash);
// each W-tile is read by the 4 co-resident mt-blocks on its XCD (L2 temporal reuse).
__global__ __launch_bounds__(256) void qkv_gemm_kernel(
    const u16* __restrict__ Ap,
    const u16* __restrict__ Wqp, const u16* __restrict__ Wkp, const u16* __restrict__ Wvp,
    const float* __restrict__ bq, const float* __restrict__ bk, const float* __restrict__ bv,
    u16* __restrict__ Qo, u16* __restrict__ Ko, u16* __restrict__ Vo) {
  const int mt = blockIdx.x, ntall = blockIdx.y;   // SWAPPED vs round 7
  const int seg = ntall >> 3, nt = ntall & 7;
  const u16* Wp = (seg == 0) ? Wqp : (seg == 1) ? Wkp : Wvp;
  const float* bp = (seg == 0) ? bq : (seg == 1) ? bk : bv;
  u16* Out = (seg == 0) ? Qo : (seg == 1) ? Ko : Vo;
  const int m0 = mt * 128, n0 = nt * 128;
  const int tid = threadIdx.x;
  const int lane = tid & 63, wave = tid >> 6;
  const int wm = (wave >> 1) * 64, wn = (wave & 1) * 64;
  const int l32 = lane & 31, khalf = lane >> 5;
  // per-lane base pointers (16B entries; u16 units = entry*8)
  const u16* apb = Ap + ((size_t)khalf * MTOT + m0 + wm + l32) * 8;
  const u16* bpb = Wp + ((size_t)khalf * 1024 + n0 + wn + l32) * 8;
  const size_t aStep = (size_t)4 * MTOT * 8;   // +4 panels per BK=32 step
  const size_t bStep = (size_t)4 * 1024 * 8;
  floatx16 acc[2][2] = {};

  auto loadfr = [&](bf16x8 (&a)[2][2], bf16x8 (&b)[2][2], int s) {
    const u16* ap = apb + (size_t)s * aStep;
    const u16* bp2 = bpb + (size_t)s * bStep;
#pragma unroll
    for (int kk = 0; kk < 2; ++kk)
#pragma unroll
      for (int i = 0; i < 2; ++i) {
        a[kk][i] = *reinterpret_cast<const bf16x8*>(ap + ((size_t)kk * 2 * MTOT + i * 32) * 8);
        b[kk][i] = *reinterpret_cast<const bf16x8*>(bp2 + ((size_t)kk * 2 * 1024 + i * 32) * 8);
      }
  };
  auto mfmall = [&](bf16x8 (&a)[2][2], bf16x8 (&b)[2][2]) {
#pragma unroll
    for (int kk = 0; kk < 2; ++kk)
#pragma unroll
      for (int i = 0; i < 2; ++i)
#pragma unroll
        for (int j = 0; j < 2; ++j)
          acc[i][j] = __builtin_amdgcn_mfma_f32_32x32x16_bf16(a[kk][i], b[kk][j], acc[i][j], 0, 0, 0);
  };

  bf16x8 aC[2][2], bC[2][2], aN[2][2], bN[2][2];
  loadfr(aC, bC, 0);
  for (int s = 0; s < 32; s += 2) {
    loadfr(aN, bN, s + 1);          // prefetch while MFMAs below execute
    mfmall(aC, bC);
    if (s + 2 < 32) loadfr(aC, bC, s + 2);
    mfmall(aN, bN);
  }
  // epilogue: C/D layout col=lane&31, row=(reg&3)+8*(reg>>2)+4*(lane>>5); row-major out.
#pragma unroll
  for (int j = 0; j < 2; ++j) {
    int col = n0 + wn + j * 32 + l32;
    float bias = bp[col];
#pragma unroll
    for (int i = 0; i < 2; ++i) {
#pragma unroll
      for (int reg = 0; reg < 16; ++reg) {
        int row = m0 + wm + i * 32 + (reg & 3) + 8 * (reg >> 2) + 4 * khalf;
        Out[(size_t)row * DD + col] = f2bf(acc[i][j][reg] + bias);
      }
    }
  }
}

// ---------------- kernel 3: mpart[pc][bh][e][d] = sum_{s in chunk pc} mask[s]*K[s,e]*V[s,d] ----------------
__global__ __launch_bounds__(256) void m_partial_kernel(
    const u16* __restrict__ Kb, const u16* __restrict__ Vb,
    const float* __restrict__ am, float* __restrict__ mpart) {
  __shared__ float sK[64 * 68];
  __shared__ float sV[64 * 68];
  const int bh = blockIdx.y;     // 0..31
  const int b = bh >> 4, h = bh & 15;
  const int tid = threadIdx.x;
  const int e0 = (tid & 15) * 4, d0 = (tid >> 4) * 4;
  float acc[4][4] = {};
  for (int cs = 0; cs < 4; ++cs) {
    const int s0 = (blockIdx.x * 4 + cs) * 64;
    if (cs) __syncthreads();  // protect LDS before restage
#pragma unroll
    for (int c = 0; c < 2; ++c) {
      int L = tid + c * 256;
      int srow = L >> 3;            // 0..63
      int col = (L & 7) * 8;        // 0..56
      size_t g = (size_t)(b * SS + s0 + srow) * DD + h * HDIM + col;
      uint4 kraw = *reinterpret_cast<const uint4*>(Kb + g);
      uint4 vraw = *reinterpret_cast<const uint4*>(Vb + g);
      float m = (am[b * SS + s0 + srow] >= 0.f) ? 1.f : 0.f;
      unsigned int kw[4] = {kraw.x, kraw.y, kraw.z, kraw.w};
      unsigned int vw[4] = {vraw.x, vraw.y, vraw.z, vraw.w};
#pragma unroll
      for (int q = 0; q < 4; ++q) {
        sK[srow * 68 + col + 2 * q]     = m * bf2f((u16)(kw[q] & 0xffffu));
        sK[srow * 68 + col + 2 * q + 1] = m * bf2f((u16)(kw[q] >> 16));
        sV[srow * 68 + col + 2 * q]     = bf2f((u16)(vw[q] & 0xffffu));
        sV[srow * 68 + col + 2 * q + 1] = bf2f((u16)(vw[q] >> 16));
      }
    }
    __syncthreads();
    for (int s = 0; s < 64; ++s) {
      float4 kk = *reinterpret_cast<const float4*>(&sK[s * 68 + e0]);
      float4 vv = *reinterpret_cast<const float4*>(&sV[s * 68 + d0]);
      float ka[4] = {kk.x, kk.y, kk.z, kk.w};
      float va[4] = {vv.x, vv.y, vv.z, vv.w};
#pragma unroll
      for (int i = 0; i < 4; ++i)
#pragma unroll
        for (int j = 0; j < 4; ++j) acc[i][j] += ka[i] * va[j];
    }
  }
  float* outp = mpart + ((size_t)(blockIdx.x * 32 + bh)) * 4096;
#pragma unroll
  for (int i = 0; i < 4; ++i) {
    float4 o = {acc[i][0], acc[i][1], acc[i][2], acc[i][3]};
    *reinterpret_cast<float4*>(&outp[(e0 + i) * 64 + d0]) = o;
  }
}

// ---------------- kernel 4: ctx[m, h*64+d] = sum_e Q[m, h*64+e] * M[bh,e,d] ----------------
__global__ __launch_bounds__(256) void ctx_kernel(
    const u16* __restrict__ Qb, const float* __restrict__ mpart, float* __restrict__ Out) {
  __shared__ float sM[64 * 68];
  __shared__ float sQ[64 * 68];
  const int mchunk = blockIdx.x;  // 0..63
  const int h = blockIdx.y;       // 0..15
  const int m0 = mchunk * 64;
  const int b = m0 >> 11;         // m0 / 2048
  const int bh = b * HH + h;
  const int tid = threadIdx.x;
#pragma unroll
  for (int c = 0; c < 4; ++c) {
    int L4 = c * 256 + tid;       // float4 index 0..1023 within the 64x64 M block
    float4 s = {0.f, 0.f, 0.f, 0.f};
#pragma unroll
    for (int pc = 0; pc < 8; ++pc) {
      const float4* p4 = reinterpret_cast<const float4*>(mpart + ((size_t)(pc * 32 + bh)) * 4096);
      float4 t = p4[L4];
      s.x += t.x; s.y += t.y; s.z += t.z; s.w += t.w;
    }
    int e = L4 >> 4, d = (L4 & 15) * 4;
    *reinterpret_cast<float4*>(&sM[e * 68 + d]) = s;
  }
#pragma unroll
  for (int c = 0; c < 2; ++c) {
    int L = tid + c * 256;
    int row = L >> 3, col = (L & 7) * 8;
    uint4 q = *reinterpret_cast<const uint4*>(Qb + (size_t)(m0 + row) * DD + h * HDIM + col);
    unsigned int w[4] = {q.x, q.y, q.z, q.w};
#pragma unroll
    for (int t = 0; t < 4; ++t) {
      sQ[row * 68 + col + 2 * t]     = bf2f((u16)(w[t] & 0xffffu));
      sQ[row * 68 + col + 2 * t + 1] = bf2f((u16)(w[t] >> 16));
    }
  }
  __syncthreads();
  const int d0 = (tid & 15) * 4, ml0 = (tid >> 4) * 4;
  float acc[4][4] = {};
  for (int e4 = 0; e4 < 64; e4 += 4) {
    float4 mm[4], qq[4];
#pragma unroll
    for (int t = 0; t < 4; ++t)
      mm[t] = *reinterpret_cast<const float4*>(&sM[(e4 + t) * 68 + d0]);
#pragma unroll
    for (int i = 0; i < 4; ++i)
      qq[i] = *reinterpret_cast<const float4*>(&sQ[(ml0 + i) * 68 + e4]);
    float ma[4][4], qa[4][4];
#pragma unroll
    for (int t = 0; t < 4; ++t) {
      ma[t][0] = mm[t].x; ma[t][1] = mm[t].y; ma[t][2] = mm[t].z; ma[t][3] = mm[t].w;
      qa[t][0] = qq[t].x; qa[t][1] = qq[t].y; qa[t][2] = qq[t].z; qa[t][3] = qq[t].w;
    }
#pragma unroll
    for (int i = 0; i < 4; ++i)
#pragma unroll
      for (int t = 0; t < 4; ++t)
#pragma unroll
        for (int j = 0; j < 4; ++j)
          acc[i][j] += qa[i][t] * ma[t][j];
  }
#pragma unroll
  for (int i = 0; i < 4; ++i) {
    float4 o = {acc[i][0], acc[i][1], acc[i][2], acc[i][3]};
    *reinterpret_cast<float4*>(Out + (size_t)(m0 + ml0 + i) * DD + h * HDIM + d0) = o;
  }
}

extern "C" void kernel_launch(void* const* d_in, const int* in_sizes, int n_in,
                              void* d_out, int out_size, void* d_ws, size_t ws_size,
                              hipStream_t stream) {
  const float* hs = (const float*)d_in[0];
  const float* am = (const float*)d_in[1];
  const float* wq = (const float*)d_in[2];
  const float* bq = (const float*)d_in[3];
  const float* wk = (const float*)d_in[4];
  const float* bk = (const float*)d_in[5];
  const float* wv = (const float*)d_in[6];
  const float* bv = (const float*)d_in[7];
  float* out = (float*)d_out;
  char* ws = (char*)d_ws;

  // workspace layout (bytes), all 16B-aligned; total ~44 MB
  u16* hs_p = (u16*)(ws);                  // 8 MiB  panel [128][4096][8] bf16
  u16* wq_p = (u16*)(ws + 8388608);        // 2 MiB  panel [128][1024][8]
  u16* wk_p = (u16*)(ws + 10485760);       // 2 MiB
  u16* wv_p = (u16*)(ws + 12582912);       // 2 MiB
  u16* q_b  = (u16*)(ws + 14680064);       // 8 MiB  row-major [4096][1024]
  u16* k_b  = (u16*)(ws + 23068672);       // 8 MiB
  u16* v_b  = (u16*)(ws + 31457280);       // 8 MiB
  float* mpart = (float*)(ws + 39845888);  // 4 MiB [8 pc][32 bh][64][64] f32

  cast_panel<<<dim3(112, 16), 256, 0, stream>>>(hs, wq, wk, wv, hs_p, wq_p, wk_p, wv_p);
  qkv_gemm_kernel<<<dim3(32, 24), 256, 0, stream>>>(hs_p, wq_p, wk_p, wv_p,
                                                    bq, bk, bv, q_b, k_b, v_b);
  m_partial_kernel<<<dim3(8, 32), 256, 0, stream>>>(k_b, v_b, am, mpart);
  ctx_kernel<<<dim3(64, 16), 256, 0, stream>>>(q_b, mpart, out);
}